// Round 2
// baseline (8363.357 us; speedup 1.0000x reference)
//
#include <hip/hip_runtime.h>
#include <cstdint>
#include <cstddef>

#define NPTS  32768
#define NB    8
#define RR    32
#define RR3   32768

typedef __bf16 bf16_t;
typedef __bf16 bf16x8 __attribute__((ext_vector_type(8)));
typedef float  f32x4  __attribute__((ext_vector_type(4)));

// adaptive load: input tensors may be fp32 or bf16 (detected at runtime)
__device__ __forceinline__ float LD(const void* p, size_t i, int isf){
  return isf ? ((const float*)p)[i] : (float)((const bf16_t*)p)[i];
}

// ---------------------------------------------------------------- reductions
__device__ __forceinline__ float wave_sum(float v){
#pragma unroll
  for (int o = 32; o > 0; o >>= 1) v += __shfl_down(v, o, 64);
  return v;
}
__device__ __forceinline__ float wave_max(float v){
#pragma unroll
  for (int o = 32; o > 0; o >>= 1) v = fmaxf(v, __shfl_down(v, o, 64));
  return v;
}

// --------------------------------------------------------------- dtype detect
// bf16 N(0,1) halfwords never have exponent 0xFF; fp32 low-mantissa halfwords
// hit it ~0.4% of the time. Scan first 786432 halfwords (== whole coords buf
// if bf16, first half if fp32 — in bounds either way).
__global__ void detect_kernel(const void* __restrict__ coords, int* __restrict__ flag){
  __shared__ int h[4];
  int t = threadIdx.x;
  const uint16_t* p = (const uint16_t*)coords;
  int hits = 0;
  for (int i = t; i < 786432; i += 256)
    hits += ((p[i] & 0x7F80) == 0x7F80) ? 1 : 0;
#pragma unroll
  for (int o = 32; o > 0; o >>= 1) hits += __shfl_down(hits, o, 64);
  if ((t & 63) == 0) h[t >> 6] = hits;
  __syncthreads();
  if (t == 0) flag[0] = (h[0] + h[1] + h[2] + h[3]) > 0 ? 1 : 0;   // 1 = fp32
}

// --------------------------------------------------------------- stats
__global__ void stats_kernel(const void* __restrict__ coords, float* __restrict__ stats,
                             const int* __restrict__ flag){
  int b = blockIdx.x, t = threadIdx.x;
  int isf = *flag;
  __shared__ float lds[12];
  __shared__ float lmax[4];
  size_t cb = ((size_t)b * 3) << 15;
  float sx = 0.f, sy = 0.f, sz = 0.f;
  for (int n = t; n < NPTS; n += 256){
    sx += LD(coords, cb + n, isf);
    sy += LD(coords, cb + NPTS + n, isf);
    sz += LD(coords, cb + 2*NPTS + n, isf);
  }
  sx = wave_sum(sx); sy = wave_sum(sy); sz = wave_sum(sz);
  int w = t >> 6, lane = t & 63;
  if (lane == 0){ lds[w] = sx; lds[4+w] = sy; lds[8+w] = sz; }
  __syncthreads();
  float mx = (lds[0]+lds[1]+lds[2]+lds[3]) * (1.f/NPTS);
  float my = (lds[4]+lds[5]+lds[6]+lds[7]) * (1.f/NPTS);
  float mz = (lds[8]+lds[9]+lds[10]+lds[11]) * (1.f/NPTS);
  float mm = 0.f;
  for (int n = t; n < NPTS; n += 256){
    float cx = LD(coords, cb + n, isf) - mx;
    float cy = LD(coords, cb + NPTS + n, isf) - my;
    float cz = LD(coords, cb + 2*NPTS + n, isf) - mz;
    mm = fmaxf(mm, cx*cx + cy*cy + cz*cz);
  }
  mm = wave_max(mm);
  if (lane == 0) lmax[w] = mm;
  __syncthreads();
  if (t == 0){
    float m = fmaxf(fmaxf(lmax[0], lmax[1]), fmaxf(lmax[2], lmax[3]));
    float inv = 32.f / (2.f * sqrtf(m) * (1.f + 1e-6f));
    float4 o; o.x = mx; o.y = my; o.z = mz; o.w = inv;
    ((float4*)stats)[b] = o;
  }
}

// --------------------------------------------------------------- corners
__device__ __forceinline__ void compute_corners(const void* __restrict__ coords, float4 st,
                                                int b, int n, int isf, int* idx, float* wts){
  size_t cbase = ((size_t)b * 3) << 15;
  float cx = LD(coords, cbase + n, isf)          - st.x;
  float cy = LD(coords, cbase + NPTS + n, isf)   - st.y;
  float cz = LD(coords, cbase + 2*NPTS + n, isf) - st.z;
  float vx = fminf(fmaxf(cx*st.w + 16.f, 0.f), 31.f);
  float vy = fminf(fmaxf(cy*st.w + 16.f, 0.f), 31.f);
  float vz = fminf(fmaxf(cz*st.w + 16.f, 0.f), 31.f);
  int lx = (int)vx, ly = (int)vy, lz = (int)vz;
  float fx = vx - (float)lx, fy = vy - (float)ly, fz = vz - (float)lz;
#pragma unroll
  for (int k = 0; k < 8; ++k){
    int dx = k >> 2, dy = (k >> 1) & 1, dz = k & 1;
    int xi = min(lx+dx, 31), yi = min(ly+dy, 31), zi = min(lz+dz, 31);
    idx[k] = (xi << 10) + (yi << 5) + zi;
    wts[k] = (dx ? fx : 1.f-fx) * (dy ? fy : 1.f-fy) * (dz ? fz : 1.f-fz);
  }
}

// --------------------------------------------------------------- scatter (atomic)
__global__ __launch_bounds__(256) void scatter_kernel(
    const void* __restrict__ feat, const void* __restrict__ coords,
    const float* __restrict__ stats, const int* __restrict__ flag,
    float* __restrict__ acc, float* __restrict__ cnt)
{
  int isf = *flag;
  int gid = blockIdx.x * 256 + threadIdx.x;       // B*N threads
  int b = gid >> 15, n = gid & (NPTS - 1);
  float4 st = ((const float4*)stats)[b];
  int idx[8]; float wts[8];
  compute_corners(coords, st, b, n, isf, idx, wts);
  float f[64];
  size_t fb = ((size_t)b << 21) + n;              // b*64*N + n
  if (isf){
    const float* fp = (const float*)feat;
#pragma unroll
    for (int c = 0; c < 64; ++c) f[c] = fp[fb + ((size_t)c << 15)];
  } else {
    const bf16_t* hp = (const bf16_t*)feat;
#pragma unroll
    for (int c = 0; c < 64; ++c) f[c] = (float)hp[fb + ((size_t)c << 15)];
  }
#pragma unroll
  for (int k = 0; k < 8; ++k){
    size_t vrow = (size_t)(b * RR3 + idx[k]);
    float w = wts[k];
    unsafeAtomicAdd(&cnt[vrow], w);
    float* ap = acc + (vrow << 6);
#pragma unroll
    for (int c = 0; c < 64; ++c) unsafeAtomicAdd(ap + c, w * f[c]);
  }
}

// --------------------------------------------------------------- normalize -> bf16 channels-last
__global__ __launch_bounds__(256) void normalize_kernel(
    const float* __restrict__ acc, const float* __restrict__ cnt, bf16_t* __restrict__ vox)
{
  int gid = blockIdx.x * 256 + threadIdx.x;       // B*R3*8 threads (8 ch each)
  int v = gid >> 3, seg = gid & 7;
  float inv = 1.f / fmaxf(cnt[v], 1e-8f);
  const f32x4* ap = (const f32x4*)acc;
  f32x4 a0 = ap[(size_t)v*16 + seg*2];
  f32x4 a1 = ap[(size_t)v*16 + seg*2 + 1];
  bf16x8 o;
  o[0] = (bf16_t)(a0[0]*inv); o[1] = (bf16_t)(a0[1]*inv);
  o[2] = (bf16_t)(a0[2]*inv); o[3] = (bf16_t)(a0[3]*inv);
  o[4] = (bf16_t)(a1[0]*inv); o[5] = (bf16_t)(a1[1]*inv);
  o[6] = (bf16_t)(a1[2]*inv); o[7] = (bf16_t)(a1[3]*inv);
  *(bf16x8*)(vox + (((size_t)v) << 6) + seg*8) = o;
}

// --------------------------------------------------------------- conv3d 3x3x3 + BN + LeakyReLU
// channels-last in/out [B*R3, 64]; tile: x fixed, y0..y0+3, z0..z0+15 (64 voxels / wg)
__global__ __launch_bounds__(256, 2) void conv3d_kernel(
    const bf16_t* __restrict__ in, const bf16_t* __restrict__ wpack,   // wpack[27][64][64]
    const float* __restrict__ scale, const float* __restrict__ shift,
    bf16_t* __restrict__ out)
{
  __shared__ bf16_t lds_in[3*6*18*72];   // 46,656 B
  __shared__ bf16_t lds_w[64*72];        //  9,216 B
  int bid = blockIdx.x;
  int b  = bid >> 9;
  int x  = (bid >> 4) & 31;
  int y0 = ((bid >> 1) & 7) << 2;
  int z0 = (bid & 1) << 4;
  int t = threadIdx.x;
  for (int seg = t; seg < 324*8; seg += 256){
    int row = seg >> 3, part = seg & 7;
    int hx = row / 108, rem = row - hx*108;
    int hy = rem / 18,  hz = rem - hy*18;
    int gx = x + hx - 1, gy = y0 + hy - 1, gz = z0 + hz - 1;
    uint4 val = make_uint4(0u,0u,0u,0u);
    if ((unsigned)gx < 32u && (unsigned)gy < 32u && (unsigned)gz < 32u)
      val = *(const uint4*)(in + ((((size_t)(b*RR3 + ((gx<<10)+(gy<<5)+gz))) << 6) + part*8));
    *(uint4*)(lds_in + row*72 + part*8) = val;
  }
  int wave = t >> 6, lane = t & 63;
  int lrow = lane & 15, quad = lane >> 4;
  f32x4 acc0 = 0.f, acc1 = 0.f, acc2 = 0.f, acc3 = 0.f;
  for (int off = 0; off < 27; ++off){
    __syncthreads();
    for (int seg = t; seg < 512; seg += 256){
      int co = seg >> 3, ci0 = (seg & 7) << 3;
      *(uint4*)(lds_w + co*72 + ci0) =
          *(const uint4*)(wpack + (size_t)off*4096 + co*64 + ci0);
    }
    __syncthreads();
    int dx = off / 9, r9 = off - dx*9, dy = r9 / 3, dz = r9 - dy*3;
    const bf16_t* arow = lds_in + ((dx*6 + wave + dy)*18 + lrow + dz) * 72;
#pragma unroll
    for (int ks = 0; ks < 2; ++ks){
      bf16x8 a  = *(const bf16x8*)(arow + ks*32 + quad*8);
      bf16x8 b0 = *(const bf16x8*)(lds_w + (     lrow)*72 + ks*32 + quad*8);
      bf16x8 b1 = *(const bf16x8*)(lds_w + (16 + lrow)*72 + ks*32 + quad*8);
      bf16x8 b2 = *(const bf16x8*)(lds_w + (32 + lrow)*72 + ks*32 + quad*8);
      bf16x8 b3 = *(const bf16x8*)(lds_w + (48 + lrow)*72 + ks*32 + quad*8);
      acc0 = __builtin_amdgcn_mfma_f32_16x16x32_bf16(a, b0, acc0, 0, 0, 0);
      acc1 = __builtin_amdgcn_mfma_f32_16x16x32_bf16(a, b1, acc1, 0, 0, 0);
      acc2 = __builtin_amdgcn_mfma_f32_16x16x32_bf16(a, b2, acc2, 0, 0, 0);
      acc3 = __builtin_amdgcn_mfma_f32_16x16x32_bf16(a, b3, acc3, 0, 0, 0);
    }
  }
  f32x4 accs[4] = {acc0, acc1, acc2, acc3};
#pragma unroll
  for (int j = 0; j < 4; ++j){
    int co = j*16 + lrow;
    float sc = scale[co], sh = shift[co];
#pragma unroll
    for (int r = 0; r < 4; ++r){
      int zl = quad*4 + r;
      size_t o = (((size_t)(b*RR3 + ((x<<10) + ((y0+wave)<<5) + z0 + zl))) << 6) + co;
      float val = accs[j][r]*sc + sh;
      val = fmaxf(val, 0.1f*val);                    // LeakyReLU(0.1)
      out[o] = (bf16_t)val;
    }
  }
}

// --------------------------------------------------------------- devoxelize + point branch
__global__ __launch_bounds__(256) void devox_kernel(
    const bf16_t* __restrict__ g,        // conv2 out [B*R3,64] channels-last
    const void* __restrict__ feat,       // [B,64,N]
    const void* __restrict__ coords,
    const void* __restrict__ mlp_w,      // [64,64]
    const float* __restrict__ stats, const int* __restrict__ flag,
    const float* __restrict__ pscale, const float* __restrict__ pshift,
    void* __restrict__ out)              // [B,64,N]
{
  __shared__ bf16_t lf[32*72];           // feat tile [p][ci]
  __shared__ bf16_t lw[64*64];           // mlp_w [o][c]
  __shared__ float  lo[64*33];           // out tile [co][p]
  int t = threadIdx.x;
  int isf = *flag;
  int pb = blockIdx.x << 5;              // 32 points / block
  int b = pb >> 15, n0 = pb & (NPTS - 1);
  size_t fbase = ((size_t)b << 21);
  for (int i = t; i < 2048; i += 256){
    int ci = i >> 5, p = i & 31;
    lf[p*72 + ci] = (bf16_t)LD(feat, fbase + ((size_t)ci << 15) + n0 + p, isf);
  }
  for (int i = t; i < 4096; i += 256)
    lw[i] = (bf16_t)LD(mlp_w, i, isf);
  __syncthreads();
  int p = t >> 3, gseg = t & 7;          // thread: point p, channels [8*gseg, 8*gseg+8)
  int n = n0 + p;
  float4 st = ((const float4*)stats)[b];
  int idx[8]; float wts[8];
  compute_corners(coords, st, b, n, isf, idx, wts);
  float dv[8] = {0,0,0,0,0,0,0,0};
#pragma unroll
  for (int k = 0; k < 8; ++k){
    bf16x8 gv = *(const bf16x8*)(g + (((size_t)(b*RR3 + idx[k])) << 6) + gseg*8);
    float w = wts[k];
#pragma unroll
    for (int j = 0; j < 8; ++j) dv[j] += w * (float)gv[j];
  }
  float pv[8] = {0,0,0,0,0,0,0,0};
#pragma unroll
  for (int s = 0; s < 8; ++s){
    bf16x8 fv = *(const bf16x8*)(lf + p*72 + s*8);
    float fvf[8];
#pragma unroll
    for (int e = 0; e < 8; ++e) fvf[e] = (float)fv[e];
#pragma unroll
    for (int j = 0; j < 8; ++j){
      bf16x8 wv = *(const bf16x8*)(lw + (gseg*8 + j)*64 + s*8);
#pragma unroll
      for (int e = 0; e < 8; ++e) pv[j] += (float)wv[e] * fvf[e];
    }
  }
#pragma unroll
  for (int j = 0; j < 8; ++j){
    int co = gseg*8 + j;
    float q = pv[j]*pscale[co] + pshift[co];
    q = fmaxf(q, 0.f);
    lo[co*33 + p] = dv[j] + q;
  }
  __syncthreads();
  size_t obase = ((size_t)b << 21) + n0;
  if (isf){
    float* of = (float*)out;
    for (int i = t; i < 2048; i += 256){
      int co = i >> 5, pp = i & 31;
      of[obase + ((size_t)co << 15) + pp] = lo[co*33 + pp];
    }
  } else {
    bf16_t* oh = (bf16_t*)out;
    for (int i = t; i < 2048; i += 256){
      int co = i >> 5, pp = i & 31;
      oh[obase + ((size_t)co << 15) + pp] = (bf16_t)lo[co*33 + pp];
    }
  }
}

// --------------------------------------------------------------- coords passthrough
__global__ __launch_bounds__(256) void copy_coords_kernel(
    const void* __restrict__ coords, void* __restrict__ out, const int* __restrict__ flag){
  int i = blockIdx.x * 256 + threadIdx.x;
  if (i >= 786432) return;
  if (*flag) ((float*)out)[16777216 + i]  = ((const float*)coords)[i];
  else       ((bf16_t*)out)[16777216 + i] = ((const bf16_t*)coords)[i];
}

// --------------------------------------------------------------- param / weight prep
__global__ void prep_weights_kernel(const void* __restrict__ w1, const void* __restrict__ w2,
                                    const int* __restrict__ flag,
                                    bf16_t* __restrict__ wp1, bf16_t* __restrict__ wp2){
  int isf = *flag;
  int id = blockIdx.x * 256 + threadIdx.x;
  if (id >= 27*64*64) return;
  int off = id >> 12, co = (id >> 6) & 63, ci = id & 63;
  int src = (co*64 + ci)*27 + off;
  wp1[id] = (bf16_t)LD(w1, src, isf);
  wp2[id] = (bf16_t)LD(w2, src, isf);
}

__global__ void prep_params_kernel(
    const void* c1b, const void* g1, const void* b1, const void* m1, const void* v1,
    const void* c2b, const void* g2, const void* b2, const void* m2, const void* v2,
    const void* pb_, const void* gp, const void* bp, const void* mp, const void* vp,
    const int* __restrict__ flag,
    float* __restrict__ P)   // [6][64]: s1, h1, s2, h2, sp, hp
{
  int isf = *flag;
  int c = threadIdx.x;
  if (c >= 64) return;
  float s1 = LD(g1,c,isf) / sqrtf(LD(v1,c,isf) + 1e-4f);
  P[c]       = s1;
  P[64 + c]  = (LD(c1b,c,isf) - LD(m1,c,isf))*s1 + LD(b1,c,isf);
  float s2 = LD(g2,c,isf) / sqrtf(LD(v2,c,isf) + 1e-4f);
  P[128 + c] = s2;
  P[192 + c] = (LD(c2b,c,isf) - LD(m2,c,isf))*s2 + LD(b2,c,isf);
  float sp = LD(gp,c,isf) / sqrtf(LD(vp,c,isf) + 1e-4f);
  P[256 + c] = sp;
  P[320 + c] = (LD(pb_,c,isf) - LD(mp,c,isf))*sp + LD(bp,c,isf);
}

// --------------------------------------------------------------- launch
extern "C" void kernel_launch(void* const* d_in, const int* in_sizes, int n_in,
                              void* d_out, int out_size, void* d_ws, size_t ws_size,
                              hipStream_t stream)
{
  const void* feat   = d_in[0];
  const void* coords = d_in[1];
  const void* c1w = d_in[2];
  const void* c1b = d_in[3];
  const void* g1  = d_in[4];
  const void* b1  = d_in[5];
  const void* m1  = d_in[6];
  const void* v1  = d_in[7];
  const void* c2w = d_in[8];
  const void* c2b = d_in[9];
  const void* g2  = d_in[10];
  const void* b2  = d_in[11];
  const void* m2  = d_in[12];
  const void* v2  = d_in[13];
  const void* mw  = d_in[14];
  const void* mb  = d_in[15];
  const void* gp  = d_in[16];
  const void* bp  = d_in[17];
  const void* mp  = d_in[18];
  const void* vp  = d_in[19];

  char* ws = (char*)d_ws;
  float*  acc   = (float*)(ws);                       // 67,108,864 B
  float*  cnt   = (float*)(ws + 67108864);            //  1,048,576 B
  bf16_t* vox   = (bf16_t*)(ws + 68157440);           // 33,554,432 B
  bf16_t* c1out = (bf16_t*)(ws);                      // reuse acc (dead after normalize)
  bf16_t* c2out = vox;                                // reuse vox (dead after conv1)
  bf16_t* wp1   = (bf16_t*)(ws + 101711872);          //    221,184 B
  bf16_t* wp2   = (bf16_t*)(ws + 101933056);          //    221,184 B
  float*  P     = (float*)(ws + 102154240);           //      1,536 B
  float*  stats = (float*)(ws + 102155776);           //        128 B
  int*    flag  = (int*)(ws + 102155904);             //        128 B  (total ~97.4 MiB)

  detect_kernel<<<1, 256, 0, stream>>>(coords, flag);
  hipMemsetAsync(acc, 0, 68157440, stream);           // acc + cnt
  prep_weights_kernel<<<432, 256, 0, stream>>>(c1w, c2w, flag, wp1, wp2);
  prep_params_kernel<<<1, 64, 0, stream>>>(c1b,g1,b1,m1,v1, c2b,g2,b2,m2,v2,
                                           mb,gp,bp,mp,vp, flag, P);
  stats_kernel<<<NB, 256, 0, stream>>>(coords, stats, flag);
  scatter_kernel<<<1024, 256, 0, stream>>>(feat, coords, stats, flag, acc, cnt);
  normalize_kernel<<<8192, 256, 0, stream>>>(acc, cnt, vox);
  conv3d_kernel<<<4096, 256, 0, stream>>>(vox,   wp1, P,       P + 64,  c1out);
  conv3d_kernel<<<4096, 256, 0, stream>>>(c1out, wp2, P + 128, P + 192, c2out);
  devox_kernel<<<8192, 256, 0, stream>>>(c2out, feat, coords, mw, stats, flag,
                                         P + 256, P + 320, d_out);
  copy_coords_kernel<<<3072, 256, 0, stream>>>(coords, d_out, flag);
}

// Round 3
// 2145.842 us; speedup vs baseline: 3.8975x; 3.8975x over previous
//
#include <hip/hip_runtime.h>
#include <cstdint>
#include <cstddef>

#define NPTS  32768
#define NB    8
#define RR    32
#define RR3   32768
#define NVOX  (NB*RR3)          // 262144
#define NCONTRIB (NB*NPTS*8)    // 2097152

typedef __bf16 bf16_t;
typedef __bf16 bf16x8 __attribute__((ext_vector_type(8)));
typedef float  f32x4  __attribute__((ext_vector_type(4)));

// adaptive load: input tensors may be fp32 or bf16 (detected at runtime)
__device__ __forceinline__ float LD(const void* p, size_t i, int isf){
  return isf ? ((const float*)p)[i] : (float)((const bf16_t*)p)[i];
}

// ---------------------------------------------------------------- reductions
__device__ __forceinline__ float wave_sum(float v){
#pragma unroll
  for (int o = 32; o > 0; o >>= 1) v += __shfl_down(v, o, 64);
  return v;
}
__device__ __forceinline__ float wave_max(float v){
#pragma unroll
  for (int o = 32; o > 0; o >>= 1) v = fmaxf(v, __shfl_down(v, o, 64));
  return v;
}

// --------------------------------------------------------------- dtype detect
__global__ void detect_kernel(const void* __restrict__ coords, int* __restrict__ flag){
  __shared__ int h[4];
  int t = threadIdx.x;
  const uint16_t* p = (const uint16_t*)coords;
  int hits = 0;
  for (int i = t; i < 786432; i += 256)
    hits += ((p[i] & 0x7F80) == 0x7F80) ? 1 : 0;
#pragma unroll
  for (int o = 32; o > 0; o >>= 1) hits += __shfl_down(hits, o, 64);
  if ((t & 63) == 0) h[t >> 6] = hits;
  __syncthreads();
  if (t == 0) flag[0] = (h[0] + h[1] + h[2] + h[3]) > 0 ? 1 : 0;   // 1 = fp32
}

// --------------------------------------------------------------- stats
__global__ void stats_kernel(const void* __restrict__ coords, float* __restrict__ stats,
                             const int* __restrict__ flag){
  int b = blockIdx.x, t = threadIdx.x;
  int isf = *flag;
  __shared__ float lds[12];
  __shared__ float lmax[4];
  size_t cb = ((size_t)b * 3) << 15;
  float sx = 0.f, sy = 0.f, sz = 0.f;
  for (int n = t; n < NPTS; n += 256){
    sx += LD(coords, cb + n, isf);
    sy += LD(coords, cb + NPTS + n, isf);
    sz += LD(coords, cb + 2*NPTS + n, isf);
  }
  sx = wave_sum(sx); sy = wave_sum(sy); sz = wave_sum(sz);
  int w = t >> 6, lane = t & 63;
  if (lane == 0){ lds[w] = sx; lds[4+w] = sy; lds[8+w] = sz; }
  __syncthreads();
  float mx = (lds[0]+lds[1]+lds[2]+lds[3]) * (1.f/NPTS);
  float my = (lds[4]+lds[5]+lds[6]+lds[7]) * (1.f/NPTS);
  float mz = (lds[8]+lds[9]+lds[10]+lds[11]) * (1.f/NPTS);
  float mm = 0.f;
  for (int n = t; n < NPTS; n += 256){
    float cx = LD(coords, cb + n, isf) - mx;
    float cy = LD(coords, cb + NPTS + n, isf) - my;
    float cz = LD(coords, cb + 2*NPTS + n, isf) - mz;
    mm = fmaxf(mm, cx*cx + cy*cy + cz*cz);
  }
  mm = wave_max(mm);
  if (lane == 0) lmax[w] = mm;
  __syncthreads();
  if (t == 0){
    float m = fmaxf(fmaxf(lmax[0], lmax[1]), fmaxf(lmax[2], lmax[3]));
    float inv = 32.f / (2.f * sqrtf(m) * (1.f + 1e-6f));
    float4 o; o.x = mx; o.y = my; o.z = mz; o.w = inv;
    ((float4*)stats)[b] = o;
  }
}

// --------------------------------------------------------------- corners
__device__ __forceinline__ void compute_corners(const void* __restrict__ coords, float4 st,
                                                int b, int n, int isf, int* idx, float* wts){
  size_t cbase = ((size_t)b * 3) << 15;
  float cx = LD(coords, cbase + n, isf)          - st.x;
  float cy = LD(coords, cbase + NPTS + n, isf)   - st.y;
  float cz = LD(coords, cbase + 2*NPTS + n, isf) - st.z;
  float vx = fminf(fmaxf(cx*st.w + 16.f, 0.f), 31.f);
  float vy = fminf(fmaxf(cy*st.w + 16.f, 0.f), 31.f);
  float vz = fminf(fmaxf(cz*st.w + 16.f, 0.f), 31.f);
  int lx = (int)vx, ly = (int)vy, lz = (int)vz;
  float fx = vx - (float)lx, fy = vy - (float)ly, fz = vz - (float)lz;
#pragma unroll
  for (int k = 0; k < 8; ++k){
    int dx = k >> 2, dy = (k >> 1) & 1, dz = k & 1;
    int xi = min(lx+dx, 31), yi = min(ly+dy, 31), zi = min(lz+dz, 31);
    idx[k] = (xi << 10) + (yi << 5) + zi;
    wts[k] = (dx ? fx : 1.f-fx) * (dy ? fy : 1.f-fy) * (dz ? fz : 1.f-fz);
  }
}

// --------------------------------------------------------------- transpose feat -> [B*N,64] bf16
__global__ __launch_bounds__(256) void transpose_kernel(
    const void* __restrict__ feat, const int* __restrict__ flag, bf16_t* __restrict__ feat_t)
{
  __shared__ float tile[64][65];
  int isf = *flag;
  int blk = blockIdx.x;            // 4096 = B * (N/64)
  int b = blk >> 9;
  int n0 = (blk & 511) << 6;
  int t = threadIdx.x, lane = t & 63, w = t >> 6;
  size_t base = ((size_t)b << 21); // b*64*N
  for (int ci = w; ci < 64; ci += 4)
    tile[ci][lane] = LD(feat, base + ((size_t)ci << 15) + n0 + lane, isf);
  __syncthreads();
  for (int i = t; i < 512; i += 256){
    int p = i >> 3, seg = i & 7;
    bf16x8 o;
#pragma unroll
    for (int e = 0; e < 8; ++e) o[e] = (bf16_t)tile[seg*8+e][p];
    *(bf16x8*)(feat_t + (((size_t)(b*NPTS + n0 + p)) << 6) + seg*8) = o;
  }
}

// --------------------------------------------------------------- voxelize: hist / offsets / fill / gather
__global__ __launch_bounds__(256) void hist_kernel(
    const void* __restrict__ coords, const float* __restrict__ stats,
    const int* __restrict__ flag, unsigned* __restrict__ hist)
{
  int isf = *flag;
  int gid = blockIdx.x*256 + threadIdx.x;
  int b = gid >> 15, n = gid & (NPTS-1);
  float4 st = ((const float4*)stats)[b];
  int idx[8]; float wts[8];
  compute_corners(coords, st, b, n, isf, idx, wts);
#pragma unroll
  for (int k = 0; k < 8; ++k) atomicAdd(&hist[(b << 15) + idx[k]], 1u);
}

__global__ __launch_bounds__(256) void offsets_kernel(
    const unsigned* __restrict__ hist, unsigned* __restrict__ offsets,
    unsigned* __restrict__ counter)
{
  int v = blockIdx.x*256 + threadIdx.x;
  int lane = threadIdx.x & 63;
  unsigned h = hist[v];
  unsigned pre = h;
#pragma unroll
  for (int o = 1; o < 64; o <<= 1){
    unsigned x = __shfl_up(pre, o, 64);
    if (lane >= o) pre += x;
  }
  unsigned total = __shfl(pre, 63, 64);
  unsigned base = 0;
  if (lane == 63) base = atomicAdd(counter, total);
  base = __shfl(base, 63, 64);
  offsets[v] = base + pre - h;      // exclusive start of segment v
}

__global__ __launch_bounds__(256) void fill_kernel(
    const void* __restrict__ coords, const float* __restrict__ stats,
    const int* __restrict__ flag, unsigned* __restrict__ offsets,
    uint2* __restrict__ sorted)
{
  int isf = *flag;
  int gid = blockIdx.x*256 + threadIdx.x;
  int b = gid >> 15, n = gid & (NPTS-1);
  float4 st = ((const float4*)stats)[b];
  int idx[8]; float wts[8];
  compute_corners(coords, st, b, n, isf, idx, wts);
#pragma unroll
  for (int k = 0; k < 8; ++k){
    unsigned pos = atomicAdd(&offsets[(b << 15) + idx[k]], 1u);   // bumps to segment end
    sorted[pos] = make_uint2((unsigned)n, __float_as_uint(wts[k]));
  }
}

// one wave per voxel; lane = channel. offsets_end[v] = segment end (post-fill offsets)
__global__ __launch_bounds__(256) void gather_kernel(
    const uint2* __restrict__ sorted, const unsigned* __restrict__ offsets_end,
    const unsigned* __restrict__ hist, const bf16_t* __restrict__ feat_t,
    bf16_t* __restrict__ vox)
{
  int v = blockIdx.x*4 + (threadIdx.x >> 6);
  int lane = threadIdx.x & 63;
  int b = v >> 15;
  unsigned end = offsets_end[v];
  unsigned cnt = hist[v];
  unsigned start = end - cnt;
  float acc = 0.f, cw = 0.f;
  for (unsigned i = start; i < end; ++i){
    uint2 e = sorted[i];
    float w = __uint_as_float(e.y);
    float f = (float)feat_t[(((size_t)((b << 15) + e.x)) << 6) + lane];
    acc += w * f;
    cw  += w;
  }
  vox[((size_t)v << 6) + lane] = (bf16_t)(acc / fmaxf(cw, 1e-8f));
}

// --------------------------------------------------------------- conv3d 3x3x3 + BN + LeakyReLU
// channels-last in/out [B*R3, 64]; tile: x fixed, y0..y0+3, z0..z0+15 (64 voxels / wg)
__global__ __launch_bounds__(256, 2) void conv3d_kernel(
    const bf16_t* __restrict__ in, const bf16_t* __restrict__ wpack,   // wpack[27][64][64]
    const float* __restrict__ scale, const float* __restrict__ shift,
    bf16_t* __restrict__ out)
{
  __shared__ bf16_t lds_in[3*6*18*72];   // 46,656 B
  __shared__ bf16_t lds_w[64*72];        //  9,216 B
  int bid = blockIdx.x;
  int b  = bid >> 9;
  int x  = (bid >> 4) & 31;
  int y0 = ((bid >> 1) & 7) << 2;
  int z0 = (bid & 1) << 4;
  int t = threadIdx.x;
  for (int seg = t; seg < 324*8; seg += 256){
    int row = seg >> 3, part = seg & 7;
    int hx = row / 108, rem = row - hx*108;
    int hy = rem / 18,  hz = rem - hy*18;
    int gx = x + hx - 1, gy = y0 + hy - 1, gz = z0 + hz - 1;
    uint4 val = make_uint4(0u,0u,0u,0u);
    if ((unsigned)gx < 32u && (unsigned)gy < 32u && (unsigned)gz < 32u)
      val = *(const uint4*)(in + ((((size_t)(b*RR3 + ((gx<<10)+(gy<<5)+gz))) << 6) + part*8));
    *(uint4*)(lds_in + row*72 + part*8) = val;
  }
  int wave = t >> 6, lane = t & 63;
  int lrow = lane & 15, quad = lane >> 4;
  f32x4 acc0 = 0.f, acc1 = 0.f, acc2 = 0.f, acc3 = 0.f;
  for (int off = 0; off < 27; ++off){
    __syncthreads();
    for (int seg = t; seg < 512; seg += 256){
      int co = seg >> 3, ci0 = (seg & 7) << 3;
      *(uint4*)(lds_w + co*72 + ci0) =
          *(const uint4*)(wpack + (size_t)off*4096 + co*64 + ci0);
    }
    __syncthreads();
    int dx = off / 9, r9 = off - dx*9, dy = r9 / 3, dz = r9 - dy*3;
    const bf16_t* arow = lds_in + ((dx*6 + wave + dy)*18 + lrow + dz) * 72;
#pragma unroll
    for (int ks = 0; ks < 2; ++ks){
      bf16x8 a  = *(const bf16x8*)(arow + ks*32 + quad*8);
      bf16x8 b0 = *(const bf16x8*)(lds_w + (     lrow)*72 + ks*32 + quad*8);
      bf16x8 b1 = *(const bf16x8*)(lds_w + (16 + lrow)*72 + ks*32 + quad*8);
      bf16x8 b2 = *(const bf16x8*)(lds_w + (32 + lrow)*72 + ks*32 + quad*8);
      bf16x8 b3 = *(const bf16x8*)(lds_w + (48 + lrow)*72 + ks*32 + quad*8);
      acc0 = __builtin_amdgcn_mfma_f32_16x16x32_bf16(a, b0, acc0, 0, 0, 0);
      acc1 = __builtin_amdgcn_mfma_f32_16x16x32_bf16(a, b1, acc1, 0, 0, 0);
      acc2 = __builtin_amdgcn_mfma_f32_16x16x32_bf16(a, b2, acc2, 0, 0, 0);
      acc3 = __builtin_amdgcn_mfma_f32_16x16x32_bf16(a, b3, acc3, 0, 0, 0);
    }
  }
  f32x4 accs[4] = {acc0, acc1, acc2, acc3};
#pragma unroll
  for (int j = 0; j < 4; ++j){
    int co = j*16 + lrow;
    float sc = scale[co], sh = shift[co];
#pragma unroll
    for (int r = 0; r < 4; ++r){
      int zl = quad*4 + r;
      size_t o = (((size_t)(b*RR3 + ((x<<10) + ((y0+wave)<<5) + z0 + zl))) << 6) + co;
      float val = accs[j][r]*sc + sh;
      val = fmaxf(val, 0.1f*val);                    // LeakyReLU(0.1)
      out[o] = (bf16_t)val;
    }
  }
}

// --------------------------------------------------------------- devoxelize + point branch
__global__ __launch_bounds__(256) void devox_kernel(
    const bf16_t* __restrict__ g,        // conv2 out [B*R3,64] channels-last
    const bf16_t* __restrict__ feat_t,   // [B*N,64] bf16 point-major
    const void* __restrict__ coords,
    const void* __restrict__ mlp_w,      // [64,64]
    const float* __restrict__ stats, const int* __restrict__ flag,
    const float* __restrict__ pscale, const float* __restrict__ pshift,
    void* __restrict__ out)              // [B,64,N]
{
  __shared__ bf16_t lf[32*72];           // feat tile [p][ci]
  __shared__ bf16_t lw[64*64];           // mlp_w [o][c]
  __shared__ float  lo[64*33];           // out tile [co][p]
  int t = threadIdx.x;
  int isf = *flag;
  int pb = blockIdx.x << 5;              // 32 points / block
  int b = pb >> 15, n0 = pb & (NPTS - 1);
  {
    int p = t >> 3, seg = t & 7;         // 256 threads == 32 points x 8 segs
    *(bf16x8*)(lf + p*72 + seg*8) =
        *(const bf16x8*)(feat_t + (((size_t)(b*NPTS + n0 + p)) << 6) + seg*8);
  }
  for (int i = t; i < 4096; i += 256)
    lw[i] = (bf16_t)LD(mlp_w, i, isf);
  __syncthreads();
  int p = t >> 3, gseg = t & 7;
  int n = n0 + p;
  float4 st = ((const float4*)stats)[b];
  int idx[8]; float wts[8];
  compute_corners(coords, st, b, n, isf, idx, wts);
  float dv[8] = {0,0,0,0,0,0,0,0};
#pragma unroll
  for (int k = 0; k < 8; ++k){
    bf16x8 gv = *(const bf16x8*)(g + (((size_t)(b*RR3 + idx[k])) << 6) + gseg*8);
    float w = wts[k];
#pragma unroll
    for (int j = 0; j < 8; ++j) dv[j] += w * (float)gv[j];
  }
  float pv[8] = {0,0,0,0,0,0,0,0};
#pragma unroll
  for (int s = 0; s < 8; ++s){
    bf16x8 fv = *(const bf16x8*)(lf + p*72 + s*8);
    float fvf[8];
#pragma unroll
    for (int e = 0; e < 8; ++e) fvf[e] = (float)fv[e];
#pragma unroll
    for (int j = 0; j < 8; ++j){
      bf16x8 wv = *(const bf16x8*)(lw + (gseg*8 + j)*64 + s*8);
#pragma unroll
      for (int e = 0; e < 8; ++e) pv[j] += (float)wv[e] * fvf[e];
    }
  }
#pragma unroll
  for (int j = 0; j < 8; ++j){
    int co = gseg*8 + j;
    float q = pv[j]*pscale[co] + pshift[co];
    q = fmaxf(q, 0.f);
    lo[co*33 + p] = dv[j] + q;
  }
  __syncthreads();
  size_t obase = ((size_t)b << 21) + n0;
  if (isf){
    float* of = (float*)out;
    for (int i = t; i < 2048; i += 256){
      int co = i >> 5, pp = i & 31;
      of[obase + ((size_t)co << 15) + pp] = lo[co*33 + pp];
    }
  } else {
    bf16_t* oh = (bf16_t*)out;
    for (int i = t; i < 2048; i += 256){
      int co = i >> 5, pp = i & 31;
      oh[obase + ((size_t)co << 15) + pp] = (bf16_t)lo[co*33 + pp];
    }
  }
}

// --------------------------------------------------------------- coords passthrough
__global__ __launch_bounds__(256) void copy_coords_kernel(
    const void* __restrict__ coords, void* __restrict__ out, const int* __restrict__ flag){
  int i = blockIdx.x * 256 + threadIdx.x;
  if (i >= 786432) return;
  if (*flag) ((float*)out)[16777216 + i]  = ((const float*)coords)[i];
  else       ((bf16_t*)out)[16777216 + i] = ((const bf16_t*)coords)[i];
}

// --------------------------------------------------------------- param / weight prep
__global__ void prep_weights_kernel(const void* __restrict__ w1, const void* __restrict__ w2,
                                    const int* __restrict__ flag,
                                    bf16_t* __restrict__ wp1, bf16_t* __restrict__ wp2){
  int isf = *flag;
  int id = blockIdx.x * 256 + threadIdx.x;
  if (id >= 27*64*64) return;
  int off = id >> 12, co = (id >> 6) & 63, ci = id & 63;
  int src = (co*64 + ci)*27 + off;
  wp1[id] = (bf16_t)LD(w1, src, isf);
  wp2[id] = (bf16_t)LD(w2, src, isf);
}

__global__ void prep_params_kernel(
    const void* c1b, const void* g1, const void* b1, const void* m1, const void* v1,
    const void* c2b, const void* g2, const void* b2, const void* m2, const void* v2,
    const void* pb_, const void* gp, const void* bp, const void* mp, const void* vp,
    const int* __restrict__ flag,
    float* __restrict__ P)   // [6][64]: s1, h1, s2, h2, sp, hp
{
  int isf = *flag;
  int c = threadIdx.x;
  if (c >= 64) return;
  float s1 = LD(g1,c,isf) / sqrtf(LD(v1,c,isf) + 1e-4f);
  P[c]       = s1;
  P[64 + c]  = (LD(c1b,c,isf) - LD(m1,c,isf))*s1 + LD(b1,c,isf);
  float s2 = LD(g2,c,isf) / sqrtf(LD(v2,c,isf) + 1e-4f);
  P[128 + c] = s2;
  P[192 + c] = (LD(c2b,c,isf) - LD(m2,c,isf))*s2 + LD(b2,c,isf);
  float sp = LD(gp,c,isf) / sqrtf(LD(vp,c,isf) + 1e-4f);
  P[256 + c] = sp;
  P[320 + c] = (LD(pb_,c,isf) - LD(mp,c,isf))*sp + LD(bp,c,isf);
}

// --------------------------------------------------------------- launch
extern "C" void kernel_launch(void* const* d_in, const int* in_sizes, int n_in,
                              void* d_out, int out_size, void* d_ws, size_t ws_size,
                              hipStream_t stream)
{
  const void* feat   = d_in[0];
  const void* coords = d_in[1];
  const void* c1w = d_in[2];
  const void* c1b = d_in[3];
  const void* g1  = d_in[4];
  const void* b1  = d_in[5];
  const void* m1  = d_in[6];
  const void* v1  = d_in[7];
  const void* c2w = d_in[8];
  const void* c2b = d_in[9];
  const void* g2  = d_in[10];
  const void* b2  = d_in[11];
  const void* m2  = d_in[12];
  const void* v2  = d_in[13];
  const void* mw  = d_in[14];
  const void* mb  = d_in[15];
  const void* gp  = d_in[16];
  const void* bp  = d_in[17];
  const void* mp  = d_in[18];
  const void* vp  = d_in[19];

  char* ws = (char*)d_ws;
  bf16_t*  feat_t  = (bf16_t*)(ws);                     // 33,554,432 B
  bf16_t*  vox     = (bf16_t*)(ws + 33554432);          // 33,554,432 B
  bf16_t*  c1out   = (bf16_t*)(ws + 67108864);          // 33,554,432 B
  bf16_t*  c2out   = vox;                               // vox dead after conv1
  uint2*   sorted  = (uint2*)(ws + 100663296);          // 16,777,216 B
  unsigned* hist   = (unsigned*)(ws + 117440512);       //  1,048,576 B
  unsigned* offs   = (unsigned*)(ws + 118489088);       //  1,048,576 B
  bf16_t*  wp1     = (bf16_t*)(ws + 119537664);         //    221,184 B
  bf16_t*  wp2     = (bf16_t*)(ws + 119758848);         //    221,184 B
  float*   P       = (float*)(ws + 119980032);          //      1,536 B
  float*   stats   = (float*)(ws + 119981568);          //        128 B
  int*     flag    = (int*)(ws + 119981696);            //        128 B
  unsigned* counter= (unsigned*)(ws + 119981824);       //        128 B  (~114.4 MiB total)

  detect_kernel<<<1, 256, 0, stream>>>(coords, flag);
  hipMemsetAsync(hist, 0, 1048576, stream);
  hipMemsetAsync(counter, 0, 4, stream);
  prep_weights_kernel<<<432, 256, 0, stream>>>(c1w, c2w, flag, wp1, wp2);
  prep_params_kernel<<<1, 64, 0, stream>>>(c1b,g1,b1,m1,v1, c2b,g2,b2,m2,v2,
                                           mb,gp,bp,mp,vp, flag, P);
  stats_kernel<<<NB, 256, 0, stream>>>(coords, stats, flag);
  transpose_kernel<<<4096, 256, 0, stream>>>(feat, flag, feat_t);
  hist_kernel<<<1024, 256, 0, stream>>>(coords, stats, flag, hist);
  offsets_kernel<<<1024, 256, 0, stream>>>(hist, offs, counter);
  fill_kernel<<<1024, 256, 0, stream>>>(coords, stats, flag, offs, sorted);
  gather_kernel<<<65536, 256, 0, stream>>>(sorted, offs, hist, feat_t, vox);
  conv3d_kernel<<<4096, 256, 0, stream>>>(vox,   wp1, P,       P + 64,  c1out);
  conv3d_kernel<<<4096, 256, 0, stream>>>(c1out, wp2, P + 128, P + 192, c2out);
  devox_kernel<<<8192, 256, 0, stream>>>(c2out, feat_t, coords, mw, stats, flag,
                                         P + 256, P + 320, d_out);
  copy_coords_kernel<<<3072, 256, 0, stream>>>(coords, d_out, flag);
}

// Round 4
// 1550.234 us; speedup vs baseline: 5.3949x; 1.3842x over previous
//
#include <hip/hip_runtime.h>
#include <cstdint>
#include <cstddef>

#define NPTS  32768
#define NB    8
#define RR    32
#define RR3   32768
#define NVOX  (NB*RR3)          // 262144

typedef __bf16 bf16_t;
typedef __bf16 bf16x8 __attribute__((ext_vector_type(8)));
typedef float  f32x4  __attribute__((ext_vector_type(4)));

// adaptive load: input tensors may be fp32 or bf16 (detected at runtime)
__device__ __forceinline__ float LD(const void* p, size_t i, int isf){
  return isf ? ((const float*)p)[i] : (float)((const bf16_t*)p)[i];
}

// ---------------------------------------------------------------- reductions
__device__ __forceinline__ float wave_sum(float v){
#pragma unroll
  for (int o = 32; o > 0; o >>= 1) v += __shfl_down(v, o, 64);
  return v;
}
__device__ __forceinline__ float wave_max(float v){
#pragma unroll
  for (int o = 32; o > 0; o >>= 1) v = fmaxf(v, __shfl_down(v, o, 64));
  return v;
}

// --------------------------------------------------------------- dtype detect (parallel)
// bf16 N(0,1) halfwords never have exponent 0xFF; fp32 low-mantissa halfwords
// hit ~0.4%. Scan 786432 halfwords (whole buf if bf16, first half if fp32).
__global__ __launch_bounds__(256) void detect_kernel(const void* __restrict__ coords,
                                                     int* __restrict__ flag){
  int i = blockIdx.x*256 + threadIdx.x;
  const uint16_t* p = (const uint16_t*)coords;
  if ((p[i] & 0x7F80) == 0x7F80) atomicOr(flag, 1);   // 1 = fp32
}

// --------------------------------------------------------------- stats (3-phase parallel)
// ssum[b*4+{0,1,2}] = sum x/y/z ; smax[b] = max norm^2 (uint-encoded) ; stats[b] = float4
__global__ __launch_bounds__(256) void stats_sum_kernel(
    const void* __restrict__ coords, const int* __restrict__ flag, float* __restrict__ ssum){
  __shared__ float l[12];
  int isf = *flag;
  int b = blockIdx.x >> 5, blk = blockIdx.x & 31;     // 32 blocks per batch
  int t = threadIdx.x;
  size_t cb = ((size_t)b * 3) << 15;
  float sx = 0.f, sy = 0.f, sz = 0.f;
  int n0 = blk << 10;
  for (int n = n0 + t; n < n0 + 1024; n += 256){
    sx += LD(coords, cb + n, isf);
    sy += LD(coords, cb + NPTS + n, isf);
    sz += LD(coords, cb + 2*NPTS + n, isf);
  }
  sx = wave_sum(sx); sy = wave_sum(sy); sz = wave_sum(sz);
  int w = t >> 6;
  if ((t & 63) == 0){ l[w] = sx; l[4+w] = sy; l[8+w] = sz; }
  __syncthreads();
  if (t == 0){
    unsafeAtomicAdd(&ssum[b*4+0], l[0]+l[1]+l[2]+l[3]);
    unsafeAtomicAdd(&ssum[b*4+1], l[4]+l[5]+l[6]+l[7]);
    unsafeAtomicAdd(&ssum[b*4+2], l[8]+l[9]+l[10]+l[11]);
  }
}

__global__ __launch_bounds__(256) void stats_max_kernel(
    const void* __restrict__ coords, const int* __restrict__ flag,
    const float* __restrict__ ssum, unsigned* __restrict__ smax){
  __shared__ float l[4];
  int isf = *flag;
  int b = blockIdx.x >> 5, blk = blockIdx.x & 31;
  int t = threadIdx.x;
  size_t cb = ((size_t)b * 3) << 15;
  float mx = ssum[b*4+0] * (1.f/NPTS);
  float my = ssum[b*4+1] * (1.f/NPTS);
  float mz = ssum[b*4+2] * (1.f/NPTS);
  float mm = 0.f;
  int n0 = blk << 10;
  for (int n = n0 + t; n < n0 + 1024; n += 256){
    float cx = LD(coords, cb + n, isf) - mx;
    float cy = LD(coords, cb + NPTS + n, isf) - my;
    float cz = LD(coords, cb + 2*NPTS + n, isf) - mz;
    mm = fmaxf(mm, cx*cx + cy*cy + cz*cz);
  }
  mm = wave_max(mm);
  int w = t >> 6;
  if ((t & 63) == 0) l[w] = mm;
  __syncthreads();
  if (t == 0){
    float m = fmaxf(fmaxf(l[0], l[1]), fmaxf(l[2], l[3]));
    atomicMax(&smax[b], __float_as_uint(m));          // valid: m >= 0
  }
}

__global__ void stats_fin_kernel(const float* __restrict__ ssum,
                                 const unsigned* __restrict__ smax,
                                 float* __restrict__ stats){
  int b = threadIdx.x;
  if (b >= NB) return;
  float m = __uint_as_float(smax[b]);
  float inv = 32.f / (2.f * sqrtf(m) * (1.f + 1e-6f));
  float4 o;
  o.x = ssum[b*4+0] * (1.f/NPTS);
  o.y = ssum[b*4+1] * (1.f/NPTS);
  o.z = ssum[b*4+2] * (1.f/NPTS);
  o.w = inv;
  ((float4*)stats)[b] = o;
}

// --------------------------------------------------------------- corners
__device__ __forceinline__ void compute_corners(const void* __restrict__ coords, float4 st,
                                                int b, int n, int isf, int* idx, float* wts){
  size_t cbase = ((size_t)b * 3) << 15;
  float cx = LD(coords, cbase + n, isf)          - st.x;
  float cy = LD(coords, cbase + NPTS + n, isf)   - st.y;
  float cz = LD(coords, cbase + 2*NPTS + n, isf) - st.z;
  float vx = fminf(fmaxf(cx*st.w + 16.f, 0.f), 31.f);
  float vy = fminf(fmaxf(cy*st.w + 16.f, 0.f), 31.f);
  float vz = fminf(fmaxf(cz*st.w + 16.f, 0.f), 31.f);
  int lx = (int)vx, ly = (int)vy, lz = (int)vz;
  float fx = vx - (float)lx, fy = vy - (float)ly, fz = vz - (float)lz;
#pragma unroll
  for (int k = 0; k < 8; ++k){
    int dx = k >> 2, dy = (k >> 1) & 1, dz = k & 1;
    int xi = min(lx+dx, 31), yi = min(ly+dy, 31), zi = min(lz+dz, 31);
    idx[k] = (xi << 10) + (yi << 5) + zi;
    wts[k] = (dx ? fx : 1.f-fx) * (dy ? fy : 1.f-fy) * (dz ? fz : 1.f-fz);
  }
}

// --------------------------------------------------------------- transpose feat -> [B*N,64] bf16
__global__ __launch_bounds__(256) void transpose_kernel(
    const void* __restrict__ feat, const int* __restrict__ flag, bf16_t* __restrict__ feat_t)
{
  __shared__ float tile[64][65];
  int isf = *flag;
  int blk = blockIdx.x;            // 4096 = B * (N/64)
  int b = blk >> 9;
  int n0 = (blk & 511) << 6;
  int t = threadIdx.x, lane = t & 63, w = t >> 6;
  size_t base = ((size_t)b << 21); // b*64*N
  for (int ci = w; ci < 64; ci += 4)
    tile[ci][lane] = LD(feat, base + ((size_t)ci << 15) + n0 + lane, isf);
  __syncthreads();
  for (int i = t; i < 512; i += 256){
    int p = i >> 3, seg = i & 7;
    bf16x8 o;
#pragma unroll
    for (int e = 0; e < 8; ++e) o[e] = (bf16_t)tile[seg*8+e][p];
    *(bf16x8*)(feat_t + (((size_t)(b*NPTS + n0 + p)) << 6) + seg*8) = o;
  }
}

// --------------------------------------------------------------- voxelize: hist / offsets / fill / gather
__global__ __launch_bounds__(256) void hist_kernel(
    const void* __restrict__ coords, const float* __restrict__ stats,
    const int* __restrict__ flag, unsigned* __restrict__ hist)
{
  int isf = *flag;
  int gid = blockIdx.x*256 + threadIdx.x;
  int b = gid >> 15, n = gid & (NPTS-1);
  float4 st = ((const float4*)stats)[b];
  int idx[8]; float wts[8];
  compute_corners(coords, st, b, n, isf, idx, wts);
#pragma unroll
  for (int k = 0; k < 8; ++k) atomicAdd(&hist[(b << 15) + idx[k]], 1u);
}

__global__ __launch_bounds__(256) void offsets_kernel(
    const unsigned* __restrict__ hist, unsigned* __restrict__ offsets,
    unsigned* __restrict__ counter)
{
  int v = blockIdx.x*256 + threadIdx.x;
  int lane = threadIdx.x & 63;
  unsigned h = hist[v];
  unsigned pre = h;
#pragma unroll
  for (int o = 1; o < 64; o <<= 1){
    unsigned x = __shfl_up(pre, o, 64);
    if (lane >= o) pre += x;
  }
  unsigned total = __shfl(pre, 63, 64);
  unsigned base = 0;
  if (lane == 63) base = atomicAdd(counter, total);
  base = __shfl(base, 63, 64);
  offsets[v] = base + pre - h;      // exclusive start of segment v
}

__global__ __launch_bounds__(256) void fill_kernel(
    const void* __restrict__ coords, const float* __restrict__ stats,
    const int* __restrict__ flag, unsigned* __restrict__ offsets,
    uint2* __restrict__ sorted)
{
  int isf = *flag;
  int gid = blockIdx.x*256 + threadIdx.x;
  int b = gid >> 15, n = gid & (NPTS-1);
  float4 st = ((const float4*)stats)[b];
  int idx[8]; float wts[8];
  compute_corners(coords, st, b, n, isf, idx, wts);
#pragma unroll
  for (int k = 0; k < 8; ++k){
    unsigned pos = atomicAdd(&offsets[(b << 15) + idx[k]], 1u);   // bumps to segment end
    sorted[pos] = make_uint2((unsigned)n, __float_as_uint(wts[k]));
  }
}

// one wave per voxel; lane = channel. offsets_end[v] = segment end (post-fill offsets)
__global__ __launch_bounds__(256) void gather_kernel(
    const uint2* __restrict__ sorted, const unsigned* __restrict__ offsets_end,
    const unsigned* __restrict__ hist, const bf16_t* __restrict__ feat_t,
    bf16_t* __restrict__ vox)
{
  int v = blockIdx.x*4 + (threadIdx.x >> 6);
  int lane = threadIdx.x & 63;
  int b = v >> 15;
  unsigned end = offsets_end[v];
  unsigned cnt = hist[v];
  unsigned start = end - cnt;
  float acc = 0.f, cw = 0.f;
  for (unsigned i = start; i < end; ++i){
    uint2 e = sorted[i];
    float w = __uint_as_float(e.y);
    float f = (float)feat_t[(((size_t)((b << 15) + e.x)) << 6) + lane];
    acc += w * f;
    cw  += w;
  }
  vox[((size_t)v << 6) + lane] = (bf16_t)(acc / fmaxf(cw, 1e-8f));
}

// --------------------------------------------------------------- conv3d 3x3x3 + BN + LeakyReLU
// channels-last in/out [B*R3, 64]; tile: x fixed, y0..y0+3, z0..z0+15 (64 voxels / wg)
__global__ __launch_bounds__(256, 2) void conv3d_kernel(
    const bf16_t* __restrict__ in, const bf16_t* __restrict__ wpack,   // wpack[27][64][64]
    const float* __restrict__ scale, const float* __restrict__ shift,
    bf16_t* __restrict__ out)
{
  __shared__ bf16_t lds_in[3*6*18*72];   // 46,656 B
  __shared__ bf16_t lds_w[64*72];        //  9,216 B
  int bid = blockIdx.x;
  int b  = bid >> 9;
  int x  = (bid >> 4) & 31;
  int y0 = ((bid >> 1) & 7) << 2;
  int z0 = (bid & 1) << 4;
  int t = threadIdx.x;
  for (int seg = t; seg < 324*8; seg += 256){
    int row = seg >> 3, part = seg & 7;
    int hx = row / 108, rem = row - hx*108;
    int hy = rem / 18,  hz = rem - hy*18;
    int gx = x + hx - 1, gy = y0 + hy - 1, gz = z0 + hz - 1;
    uint4 val = make_uint4(0u,0u,0u,0u);
    if ((unsigned)gx < 32u && (unsigned)gy < 32u && (unsigned)gz < 32u)
      val = *(const uint4*)(in + ((((size_t)(b*RR3 + ((gx<<10)+(gy<<5)+gz))) << 6) + part*8));
    *(uint4*)(lds_in + row*72 + part*8) = val;
  }
  int wave = t >> 6, lane = t & 63;
  int lrow = lane & 15, quad = lane >> 4;
  f32x4 acc0 = 0.f, acc1 = 0.f, acc2 = 0.f, acc3 = 0.f;
  for (int off = 0; off < 27; ++off){
    __syncthreads();
    for (int seg = t; seg < 512; seg += 256){
      int co = seg >> 3, ci0 = (seg & 7) << 3;
      *(uint4*)(lds_w + co*72 + ci0) =
          *(const uint4*)(wpack + (size_t)off*4096 + co*64 + ci0);
    }
    __syncthreads();
    int dx = off / 9, r9 = off - dx*9, dy = r9 / 3, dz = r9 - dy*3;
    const bf16_t* arow = lds_in + ((dx*6 + wave + dy)*18 + lrow + dz) * 72;
#pragma unroll
    for (int ks = 0; ks < 2; ++ks){
      bf16x8 a  = *(const bf16x8*)(arow + ks*32 + quad*8);
      bf16x8 b0 = *(const bf16x8*)(lds_w + (     lrow)*72 + ks*32 + quad*8);
      bf16x8 b1 = *(const bf16x8*)(lds_w + (16 + lrow)*72 + ks*32 + quad*8);
      bf16x8 b2 = *(const bf16x8*)(lds_w + (32 + lrow)*72 + ks*32 + quad*8);
      bf16x8 b3 = *(const bf16x8*)(lds_w + (48 + lrow)*72 + ks*32 + quad*8);
      acc0 = __builtin_amdgcn_mfma_f32_16x16x32_bf16(a, b0, acc0, 0, 0, 0);
      acc1 = __builtin_amdgcn_mfma_f32_16x16x32_bf16(a, b1, acc1, 0, 0, 0);
      acc2 = __builtin_amdgcn_mfma_f32_16x16x32_bf16(a, b2, acc2, 0, 0, 0);
      acc3 = __builtin_amdgcn_mfma_f32_16x16x32_bf16(a, b3, acc3, 0, 0, 0);
    }
  }
  f32x4 accs[4] = {acc0, acc1, acc2, acc3};
#pragma unroll
  for (int j = 0; j < 4; ++j){
    int co = j*16 + lrow;
    float sc = scale[co], sh = shift[co];
#pragma unroll
    for (int r = 0; r < 4; ++r){
      int zl = quad*4 + r;
      size_t o = (((size_t)(b*RR3 + ((x<<10) + ((y0+wave)<<5) + z0 + zl))) << 6) + co;
      float val = accs[j][r]*sc + sh;
      val = fmaxf(val, 0.1f*val);                    // LeakyReLU(0.1)
      out[o] = (bf16_t)val;
    }
  }
}

// --------------------------------------------------------------- devoxelize + point branch
__global__ __launch_bounds__(256) void devox_kernel(
    const bf16_t* __restrict__ g,        // conv2 out [B*R3,64] channels-last
    const bf16_t* __restrict__ feat_t,   // [B*N,64] bf16 point-major
    const void* __restrict__ coords,
    const void* __restrict__ mlp_w,      // [64,64]
    const float* __restrict__ stats, const int* __restrict__ flag,
    const float* __restrict__ pscale, const float* __restrict__ pshift,
    void* __restrict__ out)              // [B,64,N]
{
  __shared__ bf16_t lf[32*72];           // feat tile [p][ci]
  __shared__ bf16_t lw[64*64];           // mlp_w [o][c]
  __shared__ float  lo[64*33];           // out tile [co][p]
  int t = threadIdx.x;
  int isf = *flag;
  int pb = blockIdx.x << 5;              // 32 points / block
  int b = pb >> 15, n0 = pb & (NPTS - 1);
  {
    int p = t >> 3, seg = t & 7;         // 256 threads == 32 points x 8 segs
    *(bf16x8*)(lf + p*72 + seg*8) =
        *(const bf16x8*)(feat_t + (((size_t)(b*NPTS + n0 + p)) << 6) + seg*8);
  }
  for (int i = t; i < 4096; i += 256)
    lw[i] = (bf16_t)LD(mlp_w, i, isf);
  __syncthreads();
  int p = t >> 3, gseg = t & 7;
  int n = n0 + p;
  float4 st = ((const float4*)stats)[b];
  int idx[8]; float wts[8];
  compute_corners(coords, st, b, n, isf, idx, wts);
  float dv[8] = {0,0,0,0,0,0,0,0};
#pragma unroll
  for (int k = 0; k < 8; ++k){
    bf16x8 gv = *(const bf16x8*)(g + (((size_t)(b*RR3 + idx[k])) << 6) + gseg*8);
    float w = wts[k];
#pragma unroll
    for (int j = 0; j < 8; ++j) dv[j] += w * (float)gv[j];
  }
  float pv[8] = {0,0,0,0,0,0,0,0};
#pragma unroll
  for (int s = 0; s < 8; ++s){
    bf16x8 fv = *(const bf16x8*)(lf + p*72 + s*8);
    float fvf[8];
#pragma unroll
    for (int e = 0; e < 8; ++e) fvf[e] = (float)fv[e];
#pragma unroll
    for (int j = 0; j < 8; ++j){
      bf16x8 wv = *(const bf16x8*)(lw + (gseg*8 + j)*64 + s*8);
#pragma unroll
      for (int e = 0; e < 8; ++e) pv[j] += (float)wv[e] * fvf[e];
    }
  }
#pragma unroll
  for (int j = 0; j < 8; ++j){
    int co = gseg*8 + j;
    float q = pv[j]*pscale[co] + pshift[co];
    q = fmaxf(q, 0.f);
    lo[co*33 + p] = dv[j] + q;
  }
  __syncthreads();
  size_t obase = ((size_t)b << 21) + n0;
  if (isf){
    float* of = (float*)out;
    for (int i = t; i < 2048; i += 256){
      int co = i >> 5, pp = i & 31;
      of[obase + ((size_t)co << 15) + pp] = lo[co*33 + pp];
    }
  } else {
    bf16_t* oh = (bf16_t*)out;
    for (int i = t; i < 2048; i += 256){
      int co = i >> 5, pp = i & 31;
      oh[obase + ((size_t)co << 15) + pp] = (bf16_t)lo[co*33 + pp];
    }
  }
}

// --------------------------------------------------------------- coords passthrough
__global__ __launch_bounds__(256) void copy_coords_kernel(
    const void* __restrict__ coords, void* __restrict__ out, const int* __restrict__ flag){
  int i = blockIdx.x * 256 + threadIdx.x;
  if (i >= 786432) return;
  if (*flag) ((float*)out)[16777216 + i]  = ((const float*)coords)[i];
  else       ((bf16_t*)out)[16777216 + i] = ((const bf16_t*)coords)[i];
}

// --------------------------------------------------------------- param / weight prep
__global__ void prep_weights_kernel(const void* __restrict__ w1, const void* __restrict__ w2,
                                    const int* __restrict__ flag,
                                    bf16_t* __restrict__ wp1, bf16_t* __restrict__ wp2){
  int isf = *flag;
  int id = blockIdx.x * 256 + threadIdx.x;
  if (id >= 27*64*64) return;
  int off = id >> 12, co = (id >> 6) & 63, ci = id & 63;
  int src = (co*64 + ci)*27 + off;
  wp1[id] = (bf16_t)LD(w1, src, isf);
  wp2[id] = (bf16_t)LD(w2, src, isf);
}

__global__ void prep_params_kernel(
    const void* c1b, const void* g1, const void* b1, const void* m1, const void* v1,
    const void* c2b, const void* g2, const void* b2, const void* m2, const void* v2,
    const void* pb_, const void* gp, const void* bp, const void* mp, const void* vp,
    const int* __restrict__ flag,
    float* __restrict__ P)   // [6][64]: s1, h1, s2, h2, sp, hp
{
  int isf = *flag;
  int c = threadIdx.x;
  if (c >= 64) return;
  float s1 = LD(g1,c,isf) / sqrtf(LD(v1,c,isf) + 1e-4f);
  P[c]       = s1;
  P[64 + c]  = (LD(c1b,c,isf) - LD(m1,c,isf))*s1 + LD(b1,c,isf);
  float s2 = LD(g2,c,isf) / sqrtf(LD(v2,c,isf) + 1e-4f);
  P[128 + c] = s2;
  P[192 + c] = (LD(c2b,c,isf) - LD(m2,c,isf))*s2 + LD(b2,c,isf);
  float sp = LD(gp,c,isf) / sqrtf(LD(vp,c,isf) + 1e-4f);
  P[256 + c] = sp;
  P[320 + c] = (LD(pb_,c,isf) - LD(mp,c,isf))*sp + LD(bp,c,isf);
}

// --------------------------------------------------------------- launch
extern "C" void kernel_launch(void* const* d_in, const int* in_sizes, int n_in,
                              void* d_out, int out_size, void* d_ws, size_t ws_size,
                              hipStream_t stream)
{
  const void* feat   = d_in[0];
  const void* coords = d_in[1];
  const void* c1w = d_in[2];
  const void* c1b = d_in[3];
  const void* g1  = d_in[4];
  const void* b1  = d_in[5];
  const void* m1  = d_in[6];
  const void* v1  = d_in[7];
  const void* c2w = d_in[8];
  const void* c2b = d_in[9];
  const void* g2  = d_in[10];
  const void* b2  = d_in[11];
  const void* m2  = d_in[12];
  const void* v2  = d_in[13];
  const void* mw  = d_in[14];
  const void* mb  = d_in[15];
  const void* gp  = d_in[16];
  const void* bp  = d_in[17];
  const void* mp  = d_in[18];
  const void* vp  = d_in[19];

  char* ws = (char*)d_ws;
  bf16_t*  feat_t  = (bf16_t*)(ws);                     // 33,554,432 B
  bf16_t*  vox     = (bf16_t*)(ws + 33554432);          // 33,554,432 B
  bf16_t*  c1out   = (bf16_t*)(ws + 67108864);          // 33,554,432 B
  bf16_t*  c2out   = vox;                               // vox dead after conv1
  uint2*   sorted  = (uint2*)(ws + 100663296);          // 16,777,216 B
  unsigned* hist   = (unsigned*)(ws + 117440512);       //  1,048,576 B
  unsigned* offs   = (unsigned*)(ws + 118489088);       //  1,048,576 B
  bf16_t*  wp1     = (bf16_t*)(ws + 119537664);         //    221,184 B
  bf16_t*  wp2     = (bf16_t*)(ws + 119758848);         //    221,184 B
  float*   P       = (float*)(ws + 119980032);          //      1,536 B
  float*   stats   = (float*)(ws + 119981568);          //        128 B
  int*     flag    = (int*)(ws + 119981696);            //        128 B
  unsigned* counter= (unsigned*)(ws + 119981824);       //        128 B
  float*   ssum    = (float*)(ws + 119981952);          //        128 B (8x4 f32)
  unsigned* smax   = (unsigned*)(ws + 119982080);       //        128 B

  hipMemsetAsync(flag, 0, 4, stream);
  hipMemsetAsync(hist, 0, 1048576, stream);
  hipMemsetAsync(counter, 0, 4, stream);
  hipMemsetAsync(ssum, 0, 256, stream);                 // ssum + smax
  detect_kernel<<<3072, 256, 0, stream>>>(coords, flag);
  prep_weights_kernel<<<432, 256, 0, stream>>>(c1w, c2w, flag, wp1, wp2);
  prep_params_kernel<<<1, 64, 0, stream>>>(c1b,g1,b1,m1,v1, c2b,g2,b2,m2,v2,
                                           mb,gp,bp,mp,vp, flag, P);
  stats_sum_kernel<<<256, 256, 0, stream>>>(coords, flag, ssum);
  stats_max_kernel<<<256, 256, 0, stream>>>(coords, flag, ssum, smax);
  stats_fin_kernel<<<1, 64, 0, stream>>>(ssum, smax, stats);
  transpose_kernel<<<4096, 256, 0, stream>>>(feat, flag, feat_t);
  hist_kernel<<<1024, 256, 0, stream>>>(coords, stats, flag, hist);
  offsets_kernel<<<1024, 256, 0, stream>>>(hist, offs, counter);
  fill_kernel<<<1024, 256, 0, stream>>>(coords, stats, flag, offs, sorted);
  gather_kernel<<<65536, 256, 0, stream>>>(sorted, offs, hist, feat_t, vox);
  conv3d_kernel<<<4096, 256, 0, stream>>>(vox,   wp1, P,       P + 64,  c1out);
  conv3d_kernel<<<4096, 256, 0, stream>>>(c1out, wp2, P + 128, P + 192, c2out);
  devox_kernel<<<8192, 256, 0, stream>>>(c2out, feat_t, coords, mw, stats, flag,
                                         P + 256, P + 320, d_out);
  copy_coords_kernel<<<3072, 256, 0, stream>>>(coords, d_out, flag);
}

// Round 5
// 1114.136 us; speedup vs baseline: 7.5066x; 1.3914x over previous
//
#include <hip/hip_runtime.h>
#include <cstdint>
#include <cstddef>

#define NPTS  32768
#define NB    8
#define RR    32
#define RR3   32768
#define NVOX  (NB*RR3)          // 262144

typedef __bf16 bf16_t;
typedef __bf16 bf16x8 __attribute__((ext_vector_type(8)));
typedef __bf16 bf16x4 __attribute__((ext_vector_type(4)));
typedef float  f32x4  __attribute__((ext_vector_type(4)));

// adaptive load: input tensors may be fp32 or bf16 (detected at runtime)
__device__ __forceinline__ float LD(const void* p, size_t i, int isf){
  return isf ? ((const float*)p)[i] : (float)((const bf16_t*)p)[i];
}

// ---------------------------------------------------------------- reductions
__device__ __forceinline__ float wave_sum(float v){
#pragma unroll
  for (int o = 32; o > 0; o >>= 1) v += __shfl_down(v, o, 64);
  return v;
}
__device__ __forceinline__ float wave_max(float v){
#pragma unroll
  for (int o = 32; o > 0; o >>= 1) v = fmaxf(v, __shfl_down(v, o, 64));
  return v;
}

// --------------------------------------------------------------- dtype detect (parallel)
__global__ __launch_bounds__(256) void detect_kernel(const void* __restrict__ coords,
                                                     int* __restrict__ flag){
  int i = blockIdx.x*256 + threadIdx.x;
  const uint16_t* p = (const uint16_t*)coords;
  if ((p[i] & 0x7F80) == 0x7F80) atomicOr(flag, 1);   // 1 = fp32
}

// --------------------------------------------------------------- stats (3-phase parallel)
__global__ __launch_bounds__(256) void stats_sum_kernel(
    const void* __restrict__ coords, const int* __restrict__ flag, float* __restrict__ ssum){
  __shared__ float l[12];
  int isf = *flag;
  int b = blockIdx.x >> 5, blk = blockIdx.x & 31;     // 32 blocks per batch
  int t = threadIdx.x;
  size_t cb = ((size_t)b * 3) << 15;
  float sx = 0.f, sy = 0.f, sz = 0.f;
  int n0 = blk << 10;
  for (int n = n0 + t; n < n0 + 1024; n += 256){
    sx += LD(coords, cb + n, isf);
    sy += LD(coords, cb + NPTS + n, isf);
    sz += LD(coords, cb + 2*NPTS + n, isf);
  }
  sx = wave_sum(sx); sy = wave_sum(sy); sz = wave_sum(sz);
  int w = t >> 6;
  if ((t & 63) == 0){ l[w] = sx; l[4+w] = sy; l[8+w] = sz; }
  __syncthreads();
  if (t == 0){
    unsafeAtomicAdd(&ssum[b*4+0], l[0]+l[1]+l[2]+l[3]);
    unsafeAtomicAdd(&ssum[b*4+1], l[4]+l[5]+l[6]+l[7]);
    unsafeAtomicAdd(&ssum[b*4+2], l[8]+l[9]+l[10]+l[11]);
  }
}

__global__ __launch_bounds__(256) void stats_max_kernel(
    const void* __restrict__ coords, const int* __restrict__ flag,
    const float* __restrict__ ssum, unsigned* __restrict__ smax){
  __shared__ float l[4];
  int isf = *flag;
  int b = blockIdx.x >> 5, blk = blockIdx.x & 31;
  int t = threadIdx.x;
  size_t cb = ((size_t)b * 3) << 15;
  float mx = ssum[b*4+0] * (1.f/NPTS);
  float my = ssum[b*4+1] * (1.f/NPTS);
  float mz = ssum[b*4+2] * (1.f/NPTS);
  float mm = 0.f;
  int n0 = blk << 10;
  for (int n = n0 + t; n < n0 + 1024; n += 256){
    float cx = LD(coords, cb + n, isf) - mx;
    float cy = LD(coords, cb + NPTS + n, isf) - my;
    float cz = LD(coords, cb + 2*NPTS + n, isf) - mz;
    mm = fmaxf(mm, cx*cx + cy*cy + cz*cz);
  }
  mm = wave_max(mm);
  int w = t >> 6;
  if ((t & 63) == 0) l[w] = mm;
  __syncthreads();
  if (t == 0){
    float m = fmaxf(fmaxf(l[0], l[1]), fmaxf(l[2], l[3]));
    atomicMax(&smax[b], __float_as_uint(m));          // valid: m >= 0
  }
}

__global__ void stats_fin_kernel(const float* __restrict__ ssum,
                                 const unsigned* __restrict__ smax,
                                 float* __restrict__ stats){
  int b = threadIdx.x;
  if (b >= NB) return;
  float m = __uint_as_float(smax[b]);
  float inv = 32.f / (2.f * sqrtf(m) * (1.f + 1e-6f));
  float4 o;
  o.x = ssum[b*4+0] * (1.f/NPTS);
  o.y = ssum[b*4+1] * (1.f/NPTS);
  o.z = ssum[b*4+2] * (1.f/NPTS);
  o.w = inv;
  ((float4*)stats)[b] = o;
}

// --------------------------------------------------------------- corners
__device__ __forceinline__ void compute_corners(const void* __restrict__ coords, float4 st,
                                                int b, int n, int isf, int* idx, float* wts){
  size_t cbase = ((size_t)b * 3) << 15;
  float cx = LD(coords, cbase + n, isf)          - st.x;
  float cy = LD(coords, cbase + NPTS + n, isf)   - st.y;
  float cz = LD(coords, cbase + 2*NPTS + n, isf) - st.z;
  float vx = fminf(fmaxf(cx*st.w + 16.f, 0.f), 31.f);
  float vy = fminf(fmaxf(cy*st.w + 16.f, 0.f), 31.f);
  float vz = fminf(fmaxf(cz*st.w + 16.f, 0.f), 31.f);
  int lx = (int)vx, ly = (int)vy, lz = (int)vz;
  float fx = vx - (float)lx, fy = vy - (float)ly, fz = vz - (float)lz;
#pragma unroll
  for (int k = 0; k < 8; ++k){
    int dx = k >> 2, dy = (k >> 1) & 1, dz = k & 1;
    int xi = min(lx+dx, 31), yi = min(ly+dy, 31), zi = min(lz+dz, 31);
    idx[k] = (xi << 10) + (yi << 5) + zi;
    wts[k] = (dx ? fx : 1.f-fx) * (dy ? fy : 1.f-fy) * (dz ? fz : 1.f-fz);
  }
}

// --------------------------------------------------------------- transpose feat -> [B*N,64] bf16
__global__ __launch_bounds__(256) void transpose_kernel(
    const void* __restrict__ feat, const int* __restrict__ flag, bf16_t* __restrict__ feat_t)
{
  __shared__ float tile[64][65];
  int isf = *flag;
  int blk = blockIdx.x;            // 4096 = B * (N/64)
  int b = blk >> 9;
  int n0 = (blk & 511) << 6;
  int t = threadIdx.x, lane = t & 63, w = t >> 6;
  size_t base = ((size_t)b << 21); // b*64*N
  for (int ci = w; ci < 64; ci += 4)
    tile[ci][lane] = LD(feat, base + ((size_t)ci << 15) + n0 + lane, isf);
  __syncthreads();
  for (int i = t; i < 512; i += 256){
    int p = i >> 3, seg = i & 7;
    bf16x8 o;
#pragma unroll
    for (int e = 0; e < 8; ++e) o[e] = (bf16_t)tile[seg*8+e][p];
    *(bf16x8*)(feat_t + (((size_t)(b*NPTS + n0 + p)) << 6) + seg*8) = o;
  }
}

// --------------------------------------------------------------- voxelize: hist / offsets / fill / gather
__global__ __launch_bounds__(256) void hist_kernel(
    const void* __restrict__ coords, const float* __restrict__ stats,
    const int* __restrict__ flag, unsigned* __restrict__ hist)
{
  int isf = *flag;
  int gid = blockIdx.x*256 + threadIdx.x;
  int b = gid >> 15, n = gid & (NPTS-1);
  float4 st = ((const float4*)stats)[b];
  int idx[8]; float wts[8];
  compute_corners(coords, st, b, n, isf, idx, wts);
#pragma unroll
  for (int k = 0; k < 8; ++k) atomicAdd(&hist[(b << 15) + idx[k]], 1u);
}

__global__ __launch_bounds__(256) void offsets_kernel(
    const unsigned* __restrict__ hist, unsigned* __restrict__ offsets,
    unsigned* __restrict__ counter)
{
  int v = blockIdx.x*256 + threadIdx.x;
  int lane = threadIdx.x & 63;
  unsigned h = hist[v];
  unsigned pre = h;
#pragma unroll
  for (int o = 1; o < 64; o <<= 1){
    unsigned x = __shfl_up(pre, o, 64);
    if (lane >= o) pre += x;
  }
  unsigned total = __shfl(pre, 63, 64);
  unsigned base = 0;
  if (lane == 63) base = atomicAdd(counter, total);
  base = __shfl(base, 63, 64);
  offsets[v] = base + pre - h;      // exclusive start of segment v
}

__global__ __launch_bounds__(256) void fill_kernel(
    const void* __restrict__ coords, const float* __restrict__ stats,
    const int* __restrict__ flag, unsigned* __restrict__ offsets,
    uint2* __restrict__ sorted)
{
  int isf = *flag;
  int gid = blockIdx.x*256 + threadIdx.x;
  int b = gid >> 15, n = gid & (NPTS-1);
  float4 st = ((const float4*)stats)[b];
  int idx[8]; float wts[8];
  compute_corners(coords, st, b, n, isf, idx, wts);
#pragma unroll
  for (int k = 0; k < 8; ++k){
    unsigned pos = atomicAdd(&offsets[(b << 15) + idx[k]], 1u);   // bumps to segment end
    sorted[pos] = make_uint2((unsigned)n, __float_as_uint(wts[k]));
  }
}

// one wave per voxel. lane = g*16 + c4: group g in [0,4) handles contribution
// slot g (stride 4); 16 lanes per group each hold 4 channels (8B of the 128B row).
// 4-deep entry prefetch per group -> ~16x shorter critical path than serial walk.
__global__ __launch_bounds__(256) void gather_kernel(
    const uint2* __restrict__ sorted, const unsigned* __restrict__ offsets_end,
    const unsigned* __restrict__ hist, const bf16_t* __restrict__ feat_t,
    bf16_t* __restrict__ vox)
{
  int v = blockIdx.x*4 + (threadIdx.x >> 6);
  int lane = threadIdx.x & 63;
  int g  = lane >> 4;
  int c4 = lane & 15;
  int b = v >> 15;
  unsigned end = offsets_end[v];
  unsigned cnt = hist[v];
  unsigned start = end - cnt;
  f32x4 acc = 0.f;
  float cw = 0.f;
  size_t fbase = ((size_t)b << 21);      // b*NPTS*64
  for (unsigned base = start; base < end; base += 16){
    uint2 e[4];
#pragma unroll
    for (int k = 0; k < 4; ++k){
      unsigned i = base + g + 4*k;
      e[k] = (i < end) ? sorted[i] : make_uint2(0u, 0u);   // w=0 pad -> harmless row-0 load
    }
#pragma unroll
    for (int k = 0; k < 4; ++k){
      float w = __uint_as_float(e[k].y);
      bf16x4 f = *(const bf16x4*)(feat_t + fbase + ((size_t)e[k].x << 6) + c4*4);
      acc[0] += w * (float)f[0];
      acc[1] += w * (float)f[1];
      acc[2] += w * (float)f[2];
      acc[3] += w * (float)f[3];
      cw += w;
    }
  }
  // combine the 4 contribution slots (lanes differing in bits 4,5)
#pragma unroll
  for (int m = 16; m < 64; m <<= 1){
    acc[0] += __shfl_xor(acc[0], m, 64);
    acc[1] += __shfl_xor(acc[1], m, 64);
    acc[2] += __shfl_xor(acc[2], m, 64);
    acc[3] += __shfl_xor(acc[3], m, 64);
    cw     += __shfl_xor(cw, m, 64);
  }
  if (g == 0){
    float inv = 1.f / fmaxf(cw, 1e-8f);
    bf16x4 o;
    o[0] = (bf16_t)(acc[0]*inv);
    o[1] = (bf16_t)(acc[1]*inv);
    o[2] = (bf16_t)(acc[2]*inv);
    o[3] = (bf16_t)(acc[3]*inv);
    *(bf16x4*)(vox + ((size_t)v << 6) + c4*4) = o;
  }
}

// --------------------------------------------------------------- conv3d 3x3x3 + BN + LeakyReLU
// channels-last in/out [B*R3, 64]; tile: x fixed, y0..y0+3, z0..z0+15 (64 voxels / wg)
__global__ __launch_bounds__(256, 2) void conv3d_kernel(
    const bf16_t* __restrict__ in, const bf16_t* __restrict__ wpack,   // wpack[27][64][64]
    const float* __restrict__ scale, const float* __restrict__ shift,
    bf16_t* __restrict__ out)
{
  __shared__ bf16_t lds_in[3*6*18*72];   // 46,656 B
  __shared__ bf16_t lds_w[64*72];        //  9,216 B
  int bid = blockIdx.x;
  int b  = bid >> 9;
  int x  = (bid >> 4) & 31;
  int y0 = ((bid >> 1) & 7) << 2;
  int z0 = (bid & 1) << 4;
  int t = threadIdx.x;
  for (int seg = t; seg < 324*8; seg += 256){
    int row = seg >> 3, part = seg & 7;
    int hx = row / 108, rem = row - hx*108;
    int hy = rem / 18,  hz = rem - hy*18;
    int gx = x + hx - 1, gy = y0 + hy - 1, gz = z0 + hz - 1;
    uint4 val = make_uint4(0u,0u,0u,0u);
    if ((unsigned)gx < 32u && (unsigned)gy < 32u && (unsigned)gz < 32u)
      val = *(const uint4*)(in + ((((size_t)(b*RR3 + ((gx<<10)+(gy<<5)+gz))) << 6) + part*8));
    *(uint4*)(lds_in + row*72 + part*8) = val;
  }
  int wave = t >> 6, lane = t & 63;
  int lrow = lane & 15, quad = lane >> 4;
  f32x4 acc0 = 0.f, acc1 = 0.f, acc2 = 0.f, acc3 = 0.f;
  for (int off = 0; off < 27; ++off){
    __syncthreads();
    for (int seg = t; seg < 512; seg += 256){
      int co = seg >> 3, ci0 = (seg & 7) << 3;
      *(uint4*)(lds_w + co*72 + ci0) =
          *(const uint4*)(wpack + (size_t)off*4096 + co*64 + ci0);
    }
    __syncthreads();
    int dx = off / 9, r9 = off - dx*9, dy = r9 / 3, dz = r9 - dy*3;
    const bf16_t* arow = lds_in + ((dx*6 + wave + dy)*18 + lrow + dz) * 72;
#pragma unroll
    for (int ks = 0; ks < 2; ++ks){
      bf16x8 a  = *(const bf16x8*)(arow + ks*32 + quad*8);
      bf16x8 b0 = *(const bf16x8*)(lds_w + (     lrow)*72 + ks*32 + quad*8);
      bf16x8 b1 = *(const bf16x8*)(lds_w + (16 + lrow)*72 + ks*32 + quad*8);
      bf16x8 b2 = *(const bf16x8*)(lds_w + (32 + lrow)*72 + ks*32 + quad*8);
      bf16x8 b3 = *(const bf16x8*)(lds_w + (48 + lrow)*72 + ks*32 + quad*8);
      acc0 = __builtin_amdgcn_mfma_f32_16x16x32_bf16(a, b0, acc0, 0, 0, 0);
      acc1 = __builtin_amdgcn_mfma_f32_16x16x32_bf16(a, b1, acc1, 0, 0, 0);
      acc2 = __builtin_amdgcn_mfma_f32_16x16x32_bf16(a, b2, acc2, 0, 0, 0);
      acc3 = __builtin_amdgcn_mfma_f32_16x16x32_bf16(a, b3, acc3, 0, 0, 0);
    }
  }
  f32x4 accs[4] = {acc0, acc1, acc2, acc3};
#pragma unroll
  for (int j = 0; j < 4; ++j){
    int co = j*16 + lrow;
    float sc = scale[co], sh = shift[co];
#pragma unroll
    for (int r = 0; r < 4; ++r){
      int zl = quad*4 + r;
      size_t o = (((size_t)(b*RR3 + ((x<<10) + ((y0+wave)<<5) + z0 + zl))) << 6) + co;
      float val = accs[j][r]*sc + sh;
      val = fmaxf(val, 0.1f*val);                    // LeakyReLU(0.1)
      out[o] = (bf16_t)val;
    }
  }
}

// --------------------------------------------------------------- devoxelize + point branch
__global__ __launch_bounds__(256) void devox_kernel(
    const bf16_t* __restrict__ g,        // conv2 out [B*R3,64] channels-last
    const bf16_t* __restrict__ feat_t,   // [B*N,64] bf16 point-major
    const void* __restrict__ coords,
    const void* __restrict__ mlp_w,      // [64,64]
    const float* __restrict__ stats, const int* __restrict__ flag,
    const float* __restrict__ pscale, const float* __restrict__ pshift,
    void* __restrict__ out)              // [B,64,N]
{
  __shared__ bf16_t lf[32*72];           // feat tile [p][ci]
  __shared__ bf16_t lw[64*64];           // mlp_w [o][c]
  __shared__ float  lo[64*33];           // out tile [co][p]
  int t = threadIdx.x;
  int isf = *flag;
  int pb = blockIdx.x << 5;              // 32 points / block
  int b = pb >> 15, n0 = pb & (NPTS - 1);
  {
    int p = t >> 3, seg = t & 7;         // 256 threads == 32 points x 8 segs
    *(bf16x8*)(lf + p*72 + seg*8) =
        *(const bf16x8*)(feat_t + (((size_t)(b*NPTS + n0 + p)) << 6) + seg*8);
  }
  for (int i = t; i < 4096; i += 256)
    lw[i] = (bf16_t)LD(mlp_w, i, isf);
  __syncthreads();
  int p = t >> 3, gseg = t & 7;
  int n = n0 + p;
  float4 st = ((const float4*)stats)[b];
  int idx[8]; float wts[8];
  compute_corners(coords, st, b, n, isf, idx, wts);
  float dv[8] = {0,0,0,0,0,0,0,0};
#pragma unroll
  for (int k = 0; k < 8; ++k){
    bf16x8 gv = *(const bf16x8*)(g + (((size_t)(b*RR3 + idx[k])) << 6) + gseg*8);
    float w = wts[k];
#pragma unroll
    for (int j = 0; j < 8; ++j) dv[j] += w * (float)gv[j];
  }
  float pv[8] = {0,0,0,0,0,0,0,0};
#pragma unroll
  for (int s = 0; s < 8; ++s){
    bf16x8 fv = *(const bf16x8*)(lf + p*72 + s*8);
    float fvf[8];
#pragma unroll
    for (int e = 0; e < 8; ++e) fvf[e] = (float)fv[e];
#pragma unroll
    for (int j = 0; j < 8; ++j){
      bf16x8 wv = *(const bf16x8*)(lw + (gseg*8 + j)*64 + s*8);
#pragma unroll
      for (int e = 0; e < 8; ++e) pv[j] += (float)wv[e] * fvf[e];
    }
  }
#pragma unroll
  for (int j = 0; j < 8; ++j){
    int co = gseg*8 + j;
    float q = pv[j]*pscale[co] + pshift[co];
    q = fmaxf(q, 0.f);
    lo[co*33 + p] = dv[j] + q;
  }
  __syncthreads();
  size_t obase = ((size_t)b << 21) + n0;
  if (isf){
    float* of = (float*)out;
    for (int i = t; i < 2048; i += 256){
      int co = i >> 5, pp = i & 31;
      of[obase + ((size_t)co << 15) + pp] = lo[co*33 + pp];
    }
  } else {
    bf16_t* oh = (bf16_t*)out;
    for (int i = t; i < 2048; i += 256){
      int co = i >> 5, pp = i & 31;
      oh[obase + ((size_t)co << 15) + pp] = (bf16_t)lo[co*33 + pp];
    }
  }
}

// --------------------------------------------------------------- coords passthrough
__global__ __launch_bounds__(256) void copy_coords_kernel(
    const void* __restrict__ coords, void* __restrict__ out, const int* __restrict__ flag){
  int i = blockIdx.x * 256 + threadIdx.x;
  if (i >= 786432) return;
  if (*flag) ((float*)out)[16777216 + i]  = ((const float*)coords)[i];
  else       ((bf16_t*)out)[16777216 + i] = ((const bf16_t*)coords)[i];
}

// --------------------------------------------------------------- param / weight prep
__global__ void prep_weights_kernel(const void* __restrict__ w1, const void* __restrict__ w2,
                                    const int* __restrict__ flag,
                                    bf16_t* __restrict__ wp1, bf16_t* __restrict__ wp2){
  int isf = *flag;
  int id = blockIdx.x * 256 + threadIdx.x;
  if (id >= 27*64*64) return;
  int off = id >> 12, co = (id >> 6) & 63, ci = id & 63;
  int src = (co*64 + ci)*27 + off;
  wp1[id] = (bf16_t)LD(w1, src, isf);
  wp2[id] = (bf16_t)LD(w2, src, isf);
}

__global__ void prep_params_kernel(
    const void* c1b, const void* g1, const void* b1, const void* m1, const void* v1,
    const void* c2b, const void* g2, const void* b2, const void* m2, const void* v2,
    const void* pb_, const void* gp, const void* bp, const void* mp, const void* vp,
    const int* __restrict__ flag,
    float* __restrict__ P)   // [6][64]: s1, h1, s2, h2, sp, hp
{
  int isf = *flag;
  int c = threadIdx.x;
  if (c >= 64) return;
  float s1 = LD(g1,c,isf) / sqrtf(LD(v1,c,isf) + 1e-4f);
  P[c]       = s1;
  P[64 + c]  = (LD(c1b,c,isf) - LD(m1,c,isf))*s1 + LD(b1,c,isf);
  float s2 = LD(g2,c,isf) / sqrtf(LD(v2,c,isf) + 1e-4f);
  P[128 + c] = s2;
  P[192 + c] = (LD(c2b,c,isf) - LD(m2,c,isf))*s2 + LD(b2,c,isf);
  float sp = LD(gp,c,isf) / sqrtf(LD(vp,c,isf) + 1e-4f);
  P[256 + c] = sp;
  P[320 + c] = (LD(pb_,c,isf) - LD(mp,c,isf))*sp + LD(bp,c,isf);
}

// --------------------------------------------------------------- launch
extern "C" void kernel_launch(void* const* d_in, const int* in_sizes, int n_in,
                              void* d_out, int out_size, void* d_ws, size_t ws_size,
                              hipStream_t stream)
{
  const void* feat   = d_in[0];
  const void* coords = d_in[1];
  const void* c1w = d_in[2];
  const void* c1b = d_in[3];
  const void* g1  = d_in[4];
  const void* b1  = d_in[5];
  const void* m1  = d_in[6];
  const void* v1  = d_in[7];
  const void* c2w = d_in[8];
  const void* c2b = d_in[9];
  const void* g2  = d_in[10];
  const void* b2  = d_in[11];
  const void* m2  = d_in[12];
  const void* v2  = d_in[13];
  const void* mw  = d_in[14];
  const void* mb  = d_in[15];
  const void* gp  = d_in[16];
  const void* bp  = d_in[17];
  const void* mp  = d_in[18];
  const void* vp  = d_in[19];

  char* ws = (char*)d_ws;
  bf16_t*  feat_t  = (bf16_t*)(ws);                     // 33,554,432 B
  bf16_t*  vox     = (bf16_t*)(ws + 33554432);          // 33,554,432 B
  bf16_t*  c1out   = (bf16_t*)(ws + 67108864);          // 33,554,432 B
  bf16_t*  c2out   = vox;                               // vox dead after conv1
  uint2*   sorted  = (uint2*)(ws + 100663296);          // 16,777,216 B
  unsigned* hist   = (unsigned*)(ws + 117440512);       //  1,048,576 B
  unsigned* offs   = (unsigned*)(ws + 118489088);       //  1,048,576 B
  bf16_t*  wp1     = (bf16_t*)(ws + 119537664);         //    221,184 B
  bf16_t*  wp2     = (bf16_t*)(ws + 119758848);         //    221,184 B
  float*   P       = (float*)(ws + 119980032);          //      1,536 B
  float*   stats   = (float*)(ws + 119981568);          //        128 B
  int*     flag    = (int*)(ws + 119981696);            //        128 B
  unsigned* counter= (unsigned*)(ws + 119981824);       //        128 B
  float*   ssum    = (float*)(ws + 119981952);          //        128 B (8x4 f32)
  unsigned* smax   = (unsigned*)(ws + 119982080);       //        128 B

  hipMemsetAsync(flag, 0, 4, stream);
  hipMemsetAsync(hist, 0, 1048576, stream);
  hipMemsetAsync(counter, 0, 4, stream);
  hipMemsetAsync(ssum, 0, 256, stream);                 // ssum + smax
  detect_kernel<<<3072, 256, 0, stream>>>(coords, flag);
  prep_weights_kernel<<<432, 256, 0, stream>>>(c1w, c2w, flag, wp1, wp2);
  prep_params_kernel<<<1, 64, 0, stream>>>(c1b,g1,b1,m1,v1, c2b,g2,b2,m2,v2,
                                           mb,gp,bp,mp,vp, flag, P);
  stats_sum_kernel<<<256, 256, 0, stream>>>(coords, flag, ssum);
  stats_max_kernel<<<256, 256, 0, stream>>>(coords, flag, ssum, smax);
  stats_fin_kernel<<<1, 64, 0, stream>>>(ssum, smax, stats);
  transpose_kernel<<<4096, 256, 0, stream>>>(feat, flag, feat_t);
  hist_kernel<<<1024, 256, 0, stream>>>(coords, stats, flag, hist);
  offsets_kernel<<<1024, 256, 0, stream>>>(hist, offs, counter);
  fill_kernel<<<1024, 256, 0, stream>>>(coords, stats, flag, offs, sorted);
  gather_kernel<<<65536, 256, 0, stream>>>(sorted, offs, hist, feat_t, vox);
  conv3d_kernel<<<4096, 256, 0, stream>>>(vox,   wp1, P,       P + 64,  c1out);
  conv3d_kernel<<<4096, 256, 0, stream>>>(c1out, wp2, P + 128, P + 192, c2out);
  devox_kernel<<<8192, 256, 0, stream>>>(c2out, feat_t, coords, mw, stats, flag,
                                         P + 256, P + 320, d_out);
  copy_coords_kernel<<<3072, 256, 0, stream>>>(coords, d_out, flag);
}